// Round 5
// baseline (79.709 us; speedup 1.0000x reference)
//
#include <hip/hip_runtime.h>
#include <hip/hip_fp16.h>
#include <math.h>

// ---------------------------------------------------------------------------
// Single-dispatch tile-culled points splat (round 5).
// History: r2 brute force = 43.6us kernel. r3 (tile cull, fused) and r4
// (split prep+tile) both land ~78-79us total with kernels below rocprof's
// top-5 cutoff; the timed graph is dominated by harness-fixed work (268MB
// d_ws re-poison = 40.7us @83% HBM peak, d_out poison, 7 input restores,
// per-node replay gaps). r4 proved hoisting per-block prep is worth <1us, so
// fuse back to ONE kernel (fewest graph nodes) with cull-first ordering:
// bbox-only math per point (exp + 2 sqrt + rcp, ~0.3us/CU), full
// coefficients + color loads only in the rare hit branch (~8 hits/tile),
// LDS compaction, 1px/thread render over the short list.
// ---------------------------------------------------------------------------

__global__ __launch_bounds__(256) void points_one(
        const int* __restrict__ Hp, const int* __restrict__ Wp,
        const float* __restrict__ loc,     // (P,2) y,x
        const float* __restrict__ moff,    // (P,2,2)
        const float* __restrict__ msfo,    // (P,)
        const float* __restrict__ colors,  // (P,3)
        const float* __restrict__ alphas,  // (P,)
        float* __restrict__ out,           // (H,W,3)
        int P) {
    extern __shared__ float sPts[];  // P*8 floats worst case
    __shared__ int scnt;

    const int H = *Hp, W = *Wp;
    const float ratio = (float)W / (float)H;
    const float sy = 2.f / (float)max(H - 1, 1);
    const float sx = 2.f * ratio / (float)max(W - 1, 1);
    const int tilesX = (W + 15) >> 4;
    const int tilesY = (H + 15) >> 4;
    const int numTiles = tilesX * tilesY;
    const float sP = 0.5f * sqrtf((float)P);

    const float2* __restrict__ loc2  = (const float2*)loc;
    const float4* __restrict__ moff4 = (const float4*)moff;

    for (int t = blockIdx.x; t < numTiles; t += gridDim.x) {
        if (threadIdx.x == 0) scnt = 0;
        __syncthreads();

        const int tr = t / tilesX;
        const int r0 = tr << 4;
        const int c0 = (t - tr * tilesX) << 4;
        const float ty0 = -1.f + sy * (float)r0;
        const float ty1 = -1.f + sy * (float)min(r0 + 15, H - 1);
        const float tx0 = -ratio + sx * (float)c0;
        const float tx1 = -ratio + sx * (float)min(c0 + 15, W - 1);

        // ---- cull-first: bbox math only; full coefs only for hits ----
        for (int p = threadIdx.x; p < P; p += blockDim.x) {
            const float2 l = loc2[p];          // coalesced 8B
            const float4 mm = moff4[p];        // coalesced 16B
            const float s = sP * __expf(msfo[p]);
            const float T00 = mm.x + s, T01 = mm.y;
            const float T10 = mm.z,     T11 = mm.w + s;
            const float A  = T00 * T00 + T01 * T01;
            const float B  = T10 * T10 + T11 * T11;
            const float Ch = T00 * T10 + T01 * T11;  // C/2
            const float det = A * B - Ch * Ch;
            const float inv = (det > 1e-20f) ? 1.f / det : 1e30f;
            const float dy = sqrtf(B * inv) + 1e-4f;
            const float dx = sqrtf(A * inv) + 1e-4f;
            const bool hit = (l.x + dy >= ty0) && (l.x - dy <= ty1) &&
                             (l.y + dx >= tx0) && (l.y - dx <= tx1);
            if (hit) {
                const float u2 = -(T00 * l.x + T10 * l.y);
                const float v2 = -(T01 * l.x + T11 * l.y);
                const float D = 2.f * (T00 * u2 + T01 * v2);
                const float E = 2.f * (T10 * u2 + T11 * v2);
                const float G = 1.f - (u2 * u2 + v2 * v2);
                const float al = alphas[p];
                const float w0 = colors[3 * p + 0] * al;
                const float w1 = colors[3 * p + 1] * al;
                const float w2 = colors[3 * p + 2] * al;
                const unsigned bits =
                    (((unsigned)__half_as_ushort(__float2half_rn(w2))) << 16) |
                     (unsigned)__half_as_ushort(__float2half_rn(w1));
                const int slot = atomicAdd(&scnt, 1);
                float4* dst = (float4*)(sPts + 8 * slot);
                dst[0] = make_float4(A, B, 2.f * Ch, D);
                dst[1] = make_float4(E, G, w0, __uint_as_float(bits));
            }
        }
        __syncthreads();

        // ---- render: 1 px/thread over compacted list ----
        const int n = scnt;
        const int row = r0 + (threadIdx.x >> 4);
        const int col = c0 + (threadIdx.x & 15);
        if (row < H && col < W) {
            const float y = -1.f + sy * (float)row;
            const float x = -ratio + sx * (float)col;
            float a0 = 0.f, a1 = 0.f, a2 = 0.f;
            const float4* sc4 = (const float4*)sPts;
#pragma unroll 2
            for (int i = 0; i < n; ++i) {
                const float4 q0 = sc4[2 * i];      // A,B,C,D
                const float4 q1 = sc4[2 * i + 1];  // E,G,w0,pack(w1,w2)
                const float s1 = fmaf(q0.x, y, q0.w);   // A y + D
                const float s2 = fmaf(-y, s1, q1.y);    // G - y*s1
                float u = fmaf(q0.z, y, q1.x);          // C y + E
                u = fmaf(q0.y, x, u);                   // + B x
                const float m = fmaxf(fmaf(-x, u, s2), 0.f);
                const unsigned bits = __float_as_uint(q1.w);
                a0 = fmaf(m, q1.z, a0);
                a1 = fmaf(m, __half2float(__ushort_as_half((unsigned short)(bits & 0xffffu))), a1);
                a2 = fmaf(m, __half2float(__ushort_as_half((unsigned short)(bits >> 16))), a2);
            }
            float* o = out + 3 * ((size_t)row * W + col);
            o[0] = 1.f / (1.f + __expf(-4.f * a0));
            o[1] = 1.f / (1.f + __expf(-4.f * a1));
            o[2] = 1.f / (1.f + __expf(-4.f * a2));
        }
        __syncthreads();  // protect sPts/scnt before next tile
    }
}

extern "C" void kernel_launch(void* const* d_in, const int* in_sizes, int n_in,
                              void* d_out, int out_size, void* d_ws, size_t ws_size,
                              hipStream_t stream) {
    const int*   Hp     = (const int*)d_in[0];
    const int*   Wp     = (const int*)d_in[1];
    const float* loc    = (const float*)d_in[2];  // (1,1,P,2)
    const float* moff   = (const float*)d_in[3];  // (P,2,2)
    const float* msfo   = (const float*)d_in[4];  // (P,1,1)
    const float* colors = (const float*)d_in[5];  // (1,1,P,3)
    const float* alphas = (const float*)d_in[6];  // (1,1,P,1)
    float* out = (float*)d_out;

    const int P = in_sizes[3] / 4;       // matrix_offsets: P*2*2 elements
    const int total_pix = out_size / 3;  // H*W

    const int block = 256;
    const int grid = (total_pix + block - 1) / block;  // ~= numTiles (16x16)
    const size_t lds = (size_t)P * 8 * sizeof(float);
    points_one<<<grid, block, lds, stream>>>(
        Hp, Wp, loc, moff, msfo, colors, alphas, out, P);
}